// Round 1
// baseline (1760.511 us; speedup 1.0000x reference)
//
#include <hip/hip_runtime.h>
#include <math.h>

// Problem constants (fixed by setup_inputs in the reference)
#define IN   128
#define HID  256
#define OUT  64
#define N0   400000
#define N1T  40000
#define N2T  4000
#define E1   640000
#define E2   64000

// ---------------------------------------------------------------------------
// scatter1: per edge e, agg1[dst1[e]][:] += x[src1[e]][:]  (IN=128 floats)
// 32 lanes per edge, float4 per lane. Also counts degree (lane 0).
// ---------------------------------------------------------------------------
__global__ __launch_bounds__(256) void scatter1_kernel(
    const float* __restrict__ x,
    const int* __restrict__ src, const int* __restrict__ dst,
    float* __restrict__ agg, float* __restrict__ deg)
{
    int e = blockIdx.x * 8 + (threadIdx.x >> 5);
    if (e >= E1) return;
    int lane = threadIdx.x & 31;
    int s = src[e];
    int d = dst[e];
    const float4* xr = reinterpret_cast<const float4*>(x + (size_t)s * IN);
    float4 v = xr[lane];
    float* ar = agg + (size_t)d * IN + lane * 4;
    atomicAdd(ar + 0, v.x);
    atomicAdd(ar + 1, v.y);
    atomicAdd(ar + 2, v.z);
    atomicAdd(ar + 3, v.w);
    if (lane == 0) atomicAdd(deg + d, 1.0f);
}

// ---------------------------------------------------------------------------
// layer1: h[i][j] = relu( (agg1[i]/max(deg,1)) . w_l1[:,j] + b_l1[j]
//                         + x[i] . w_r1[:,j] ),  i < N1T, j < HID
// 16 rows per block, 256 threads (one output column each).
// ---------------------------------------------------------------------------
__global__ __launch_bounds__(256) void layer1_kernel(
    const float* __restrict__ x,
    const float* __restrict__ agg, const float* __restrict__ deg,
    const float* __restrict__ w_l, const float* __restrict__ b_l,
    const float* __restrict__ w_r, float* __restrict__ h)
{
    __shared__ float a_s[16][IN];
    __shared__ float x_s[16][IN];
    __shared__ float inv_s[16];
    const int r0 = blockIdx.x * 16;
    const int tid = threadIdx.x;

    if (tid < 16) {
        float dg = deg[r0 + tid];
        inv_s[tid] = 1.0f / fmaxf(dg, 1.0f);
    }
    __syncthreads();

    for (int i = tid; i < 16 * IN; i += 256) {
        int r = i >> 7;      // /128
        int k = i & 127;
        a_s[r][k] = agg[(size_t)(r0 + r) * IN + k] * inv_s[r];
        x_s[r][k] = x[(size_t)(r0 + r) * IN + k];
    }
    __syncthreads();

    float acc[16];
#pragma unroll
    for (int r = 0; r < 16; ++r) acc[r] = 0.0f;

    const int j = tid;  // output column 0..255
    for (int k = 0; k < IN; ++k) {
        float wl = w_l[k * HID + j];
        float wr = w_r[k * HID + j];
#pragma unroll
        for (int r = 0; r < 16; ++r)
            acc[r] += a_s[r][k] * wl + x_s[r][k] * wr;
    }

    float b = b_l[j];
#pragma unroll
    for (int r = 0; r < 16; ++r) {
        h[(size_t)(r0 + r) * HID + j] = fmaxf(acc[r] + b, 0.0f);
    }
}

// ---------------------------------------------------------------------------
// scatter2: per edge e, agg2[dst2[e]][:] += h[src2[e]][:]  (HID=256 floats)
// 64 lanes per edge, float4 per lane.
// ---------------------------------------------------------------------------
__global__ __launch_bounds__(256) void scatter2_kernel(
    const float* __restrict__ h,
    const int* __restrict__ src, const int* __restrict__ dst,
    float* __restrict__ agg, float* __restrict__ deg)
{
    int e = blockIdx.x * 4 + (threadIdx.x >> 6);
    if (e >= E2) return;
    int lane = threadIdx.x & 63;
    int s = src[e];
    int d = dst[e];
    const float4* hr = reinterpret_cast<const float4*>(h + (size_t)s * HID);
    float4 v = hr[lane];
    float* ar = agg + (size_t)d * HID + lane * 4;
    atomicAdd(ar + 0, v.x);
    atomicAdd(ar + 1, v.y);
    atomicAdd(ar + 2, v.z);
    atomicAdd(ar + 3, v.w);
    if (lane == 0) atomicAdd(deg + d, 1.0f);
}

// ---------------------------------------------------------------------------
// layer2 + log_softmax: one wave (64 threads) per output row.
// out[i][j] = logsoftmax_j( (agg2[i]/deg) . w_l2[:,j] + b_l2[j] + h[i] . w_r2[:,j] )
// ---------------------------------------------------------------------------
__global__ __launch_bounds__(64) void layer2_kernel(
    const float* __restrict__ h,
    const float* __restrict__ agg, const float* __restrict__ deg,
    const float* __restrict__ w_l, const float* __restrict__ b_l,
    const float* __restrict__ w_r, float* __restrict__ out)
{
    __shared__ float a_s[HID];
    __shared__ float h_s[HID];
    const int i = blockIdx.x;
    const int j = threadIdx.x;  // 0..63

    float inv = 1.0f / fmaxf(deg[i], 1.0f);
    const float4* ar = reinterpret_cast<const float4*>(agg + (size_t)i * HID);
    const float4* hr = reinterpret_cast<const float4*>(h + (size_t)i * HID);
    float4 av = ar[j];
    float4 hv = hr[j];
    reinterpret_cast<float4*>(a_s)[j] = make_float4(av.x * inv, av.y * inv, av.z * inv, av.w * inv);
    reinterpret_cast<float4*>(h_s)[j] = hv;
    __syncthreads();

    float acc = b_l[j];
    for (int k = 0; k < HID; ++k) {
        acc += a_s[k] * w_l[k * OUT + j] + h_s[k] * w_r[k * OUT + j];
    }

    // wave-wide (64-lane) log_softmax
    float m = acc;
#pragma unroll
    for (int off = 32; off; off >>= 1) m = fmaxf(m, __shfl_xor(m, off));
    float ex = expf(acc - m);
#pragma unroll
    for (int off = 32; off; off >>= 1) ex += __shfl_xor(ex, off);
    // ex now holds the row sum in every lane
    out[(size_t)i * OUT + j] = acc - m - logf(ex);
}

// ---------------------------------------------------------------------------
extern "C" void kernel_launch(void* const* d_in, const int* in_sizes, int n_in,
                              void* d_out, int out_size, void* d_ws, size_t ws_size,
                              hipStream_t stream)
{
    const float* x    = (const float*)d_in[0];
    const int*   src1 = (const int*)  d_in[1];
    const int*   dst1 = (const int*)  d_in[2];
    const int*   src2 = (const int*)  d_in[3];
    const int*   dst2 = (const int*)  d_in[4];
    const float* w_l1 = (const float*)d_in[5];
    const float* b_l1 = (const float*)d_in[6];
    const float* w_r1 = (const float*)d_in[7];
    const float* w_l2 = (const float*)d_in[8];
    const float* b_l2 = (const float*)d_in[9];
    const float* w_r2 = (const float*)d_in[10];
    float* out = (float*)d_out;

    // Workspace layout (floats):
    // [agg1: N1T*IN | deg1: N1T | agg2: N2T*HID | deg2: N2T | h: N1T*HID]
    float* ws   = (float*)d_ws;
    float* agg1 = ws;
    float* deg1 = agg1 + (size_t)N1T * IN;
    float* agg2 = deg1 + N1T;
    float* deg2 = agg2 + (size_t)N2T * HID;
    float* h    = deg2 + N2T;

    size_t zero_floats = (size_t)N1T * IN + N1T + (size_t)N2T * HID + N2T;
    hipMemsetAsync(d_ws, 0, zero_floats * sizeof(float), stream);

    scatter1_kernel<<<E1 / 8, 256, 0, stream>>>(x, src1, dst1, agg1, deg1);
    layer1_kernel<<<N1T / 16, 256, 0, stream>>>(x, agg1, deg1, w_l1, b_l1, w_r1, h);
    scatter2_kernel<<<E2 / 4, 256, 0, stream>>>(h, src2, dst2, agg2, deg2);
    layer2_kernel<<<N2T, 64, 0, stream>>>(h, agg2, deg2, w_l2, b_l2, w_r2, out);
}

// Round 2
// 734.688 us; speedup vs baseline: 2.3963x; 2.3963x over previous
//
#include <hip/hip_runtime.h>
#include <math.h>

// Problem constants (fixed by setup_inputs in the reference)
#define IN   128
#define HID  256
#define OUT  64
#define N0   400000
#define N1T  40000
#define N2T  4000
#define E1   640000
#define E2   64000

// ---------------------------------------------------------------------------
// hist: count in-degree of every target node for both edge sets.
// ---------------------------------------------------------------------------
__global__ __launch_bounds__(256) void hist_kernel(
    const int* __restrict__ dst1, const int* __restrict__ dst2,
    int* __restrict__ cnt1, int* __restrict__ cnt2)
{
    int e = blockIdx.x * 256 + threadIdx.x;
    if (e < E1) {
        atomicAdd(&cnt1[dst1[e]], 1);
    } else if (e < E1 + E2) {
        atomicAdd(&cnt2[dst2[e - E1]], 1);
    }
}

// ---------------------------------------------------------------------------
// scan: single-block exclusive scan, off[0..n] (off[n] = total), cur = copy.
// ---------------------------------------------------------------------------
__global__ __launch_bounds__(1024) void scan_kernel(
    const int* __restrict__ cnt, int* __restrict__ off, int* __restrict__ cur, int n)
{
    __shared__ int sums[1024];
    const int t = threadIdx.x;
    const int chunk = (n + 1023) >> 10;
    const int begin = t * chunk;
    const int end = min(begin + chunk, n);

    int s = 0;
    for (int i = begin; i < end; ++i) s += cnt[i];
    sums[t] = s;
    __syncthreads();

    // Hillis-Steele inclusive scan of chunk sums
    for (int d = 1; d < 1024; d <<= 1) {
        int tmp = (t >= d) ? sums[t - d] : 0;
        __syncthreads();
        sums[t] += tmp;
        __syncthreads();
    }

    int run = sums[t] - s;  // exclusive prefix at chunk start
    for (int i = begin; i < end; ++i) {
        off[i] = run;
        cur[i] = run;
        run += cnt[i];
    }
    if (end == n && begin < n) off[n] = run;
    if (n == 0 && t == 0) off[0] = 0;
}

// ---------------------------------------------------------------------------
// scatter_idx: bucket edges by dst (CSR build). Order within bucket is
// nondeterministic (atomic cursor) — only affects fp summation order.
// ---------------------------------------------------------------------------
__global__ __launch_bounds__(256) void scatter_idx_kernel(
    const int* __restrict__ src1, const int* __restrict__ dst1,
    const int* __restrict__ src2, const int* __restrict__ dst2,
    int* __restrict__ cur1, int* __restrict__ cur2,
    int* __restrict__ ss1, int* __restrict__ ss2)
{
    int e = blockIdx.x * 256 + threadIdx.x;
    if (e < E1) {
        int pos = atomicAdd(&cur1[dst1[e]], 1);
        ss1[pos] = src1[e];
    } else if (e < E1 + E2) {
        int ee = e - E1;
        int pos = atomicAdd(&cur2[dst2[ee]], 1);
        ss2[pos] = src2[ee];
    }
}

// ---------------------------------------------------------------------------
// gather1: per target row i (one wave), agg1[i] = mean of x[ss1[...]] rows.
// 64 lanes x float2 = 128 cols.
// ---------------------------------------------------------------------------
__global__ __launch_bounds__(256) void gather1_kernel(
    const float* __restrict__ x,
    const int* __restrict__ off, const int* __restrict__ ss,
    float* __restrict__ agg)
{
    int row = blockIdx.x * 4 + (threadIdx.x >> 6);
    if (row >= N1T) return;
    int lane = threadIdx.x & 63;
    int b = off[row], en = off[row + 1];

    float2 acc = make_float2(0.0f, 0.0f);
    for (int e = b; e < en; ++e) {
        int s = ss[e];
        float2 v = reinterpret_cast<const float2*>(x + (size_t)s * IN)[lane];
        acc.x += v.x;
        acc.y += v.y;
    }
    float inv = 1.0f / fmaxf((float)(en - b), 1.0f);
    acc.x *= inv;
    acc.y *= inv;
    reinterpret_cast<float2*>(agg + (size_t)row * IN)[lane] = acc;
}

// ---------------------------------------------------------------------------
// gather2: per target row i (one wave), agg2[i] = mean of h[ss2[...]] rows.
// 64 lanes x float4 = 256 cols.
// ---------------------------------------------------------------------------
__global__ __launch_bounds__(256) void gather2_kernel(
    const float* __restrict__ h,
    const int* __restrict__ off, const int* __restrict__ ss,
    float* __restrict__ agg)
{
    int row = blockIdx.x * 4 + (threadIdx.x >> 6);
    if (row >= N2T) return;
    int lane = threadIdx.x & 63;
    int b = off[row], en = off[row + 1];

    float4 acc = make_float4(0.0f, 0.0f, 0.0f, 0.0f);
    for (int e = b; e < en; ++e) {
        int s = ss[e];
        float4 v = reinterpret_cast<const float4*>(h + (size_t)s * HID)[lane];
        acc.x += v.x; acc.y += v.y; acc.z += v.z; acc.w += v.w;
    }
    float inv = 1.0f / fmaxf((float)(en - b), 1.0f);
    acc.x *= inv; acc.y *= inv; acc.z *= inv; acc.w *= inv;
    reinterpret_cast<float4*>(agg + (size_t)row * HID)[lane] = acc;
}

// ---------------------------------------------------------------------------
// layer1: h[i][j] = relu( agg1[i] . w_l1[:,j] + b_l1[j] + x[i] . w_r1[:,j] )
// 16 rows per block, 256 threads (one output column each). agg1 already mean.
// ---------------------------------------------------------------------------
__global__ __launch_bounds__(256) void layer1_kernel(
    const float* __restrict__ x,
    const float* __restrict__ agg,
    const float* __restrict__ w_l, const float* __restrict__ b_l,
    const float* __restrict__ w_r, float* __restrict__ h)
{
    __shared__ float a_s[16][IN];
    __shared__ float x_s[16][IN];
    const int r0 = blockIdx.x * 16;
    const int tid = threadIdx.x;

    for (int i = tid; i < 16 * IN; i += 256) {
        int r = i >> 7;      // /128
        int k = i & 127;
        a_s[r][k] = agg[(size_t)(r0 + r) * IN + k];
        x_s[r][k] = x[(size_t)(r0 + r) * IN + k];
    }
    __syncthreads();

    float acc[16];
#pragma unroll
    for (int r = 0; r < 16; ++r) acc[r] = 0.0f;

    const int j = tid;  // output column 0..255
    for (int k = 0; k < IN; ++k) {
        float wl = w_l[k * HID + j];
        float wr = w_r[k * HID + j];
#pragma unroll
        for (int r = 0; r < 16; ++r)
            acc[r] += a_s[r][k] * wl + x_s[r][k] * wr;
    }

    float b = b_l[j];
#pragma unroll
    for (int r = 0; r < 16; ++r) {
        h[(size_t)(r0 + r) * HID + j] = fmaxf(acc[r] + b, 0.0f);
    }
}

// ---------------------------------------------------------------------------
// layer2 + log_softmax: one wave (64 threads) per output row. agg2 already mean.
// ---------------------------------------------------------------------------
__global__ __launch_bounds__(64) void layer2_kernel(
    const float* __restrict__ h,
    const float* __restrict__ agg,
    const float* __restrict__ w_l, const float* __restrict__ b_l,
    const float* __restrict__ w_r, float* __restrict__ out)
{
    __shared__ float a_s[HID];
    __shared__ float h_s[HID];
    const int i = blockIdx.x;
    const int j = threadIdx.x;  // 0..63

    const float4* ar = reinterpret_cast<const float4*>(agg + (size_t)i * HID);
    const float4* hr = reinterpret_cast<const float4*>(h + (size_t)i * HID);
    reinterpret_cast<float4*>(a_s)[j] = ar[j];
    reinterpret_cast<float4*>(h_s)[j] = hr[j];
    __syncthreads();

    float acc = b_l[j];
    for (int k = 0; k < HID; ++k) {
        acc += a_s[k] * w_l[k * OUT + j] + h_s[k] * w_r[k * OUT + j];
    }

    // wave-wide (64-lane) log_softmax
    float m = acc;
#pragma unroll
    for (int off = 32; off; off >>= 1) m = fmaxf(m, __shfl_xor(m, off));
    float ex = expf(acc - m);
#pragma unroll
    for (int off = 32; off; off >>= 1) ex += __shfl_xor(ex, off);
    out[(size_t)i * OUT + j] = acc - m - logf(ex);
}

// ---------------------------------------------------------------------------
extern "C" void kernel_launch(void* const* d_in, const int* in_sizes, int n_in,
                              void* d_out, int out_size, void* d_ws, size_t ws_size,
                              hipStream_t stream)
{
    const float* x    = (const float*)d_in[0];
    const int*   src1 = (const int*)  d_in[1];
    const int*   dst1 = (const int*)  d_in[2];
    const int*   src2 = (const int*)  d_in[3];
    const int*   dst2 = (const int*)  d_in[4];
    const float* w_l1 = (const float*)d_in[5];
    const float* b_l1 = (const float*)d_in[6];
    const float* w_r1 = (const float*)d_in[7];
    const float* w_l2 = (const float*)d_in[8];
    const float* b_l2 = (const float*)d_in[9];
    const float* w_r2 = (const float*)d_in[10];
    float* out = (float*)d_out;

    // Workspace layout:
    // ints:  [cnt1:N1T | cnt2:N2T | off1:N1T+1 | off2:N2T+1 | cur1:N1T | cur2:N2T | ss1:E1 | ss2:E2]
    // floats:[agg1:N1T*IN | agg2:N2T*HID | h:N1T*HID]
    int* ws_i = (int*)d_ws;
    int* cnt1 = ws_i;
    int* cnt2 = cnt1 + N1T;
    int* off1 = cnt2 + N2T;
    int* off2 = off1 + N1T + 1;
    int* cur1 = off2 + N2T + 1;
    int* cur2 = cur1 + N1T;
    int* ss1  = cur2 + N2T;
    int* ss2  = ss1 + E1;
    float* agg1 = (float*)(ss2 + E2);
    float* agg2 = agg1 + (size_t)N1T * IN;
    float* h    = agg2 + (size_t)N2T * HID;

    // zero only the histogram counters
    hipMemsetAsync(cnt1, 0, (N1T + N2T) * sizeof(int), stream);

    const int ET = E1 + E2;
    hist_kernel<<<(ET + 255) / 256, 256, 0, stream>>>(dst1, dst2, cnt1, cnt2);
    scan_kernel<<<1, 1024, 0, stream>>>(cnt1, off1, cur1, N1T);
    scan_kernel<<<1, 1024, 0, stream>>>(cnt2, off2, cur2, N2T);
    scatter_idx_kernel<<<(ET + 255) / 256, 256, 0, stream>>>(src1, dst1, src2, dst2,
                                                             cur1, cur2, ss1, ss2);
    gather1_kernel<<<(N1T + 3) / 4, 256, 0, stream>>>(x, off1, ss1, agg1);
    layer1_kernel<<<N1T / 16, 256, 0, stream>>>(x, agg1, w_l1, b_l1, w_r1, h);
    gather2_kernel<<<(N2T + 3) / 4, 256, 0, stream>>>(h, off2, ss2, agg2);
    layer2_kernel<<<N2T, 64, 0, stream>>>(h, agg2, w_l2, b_l2, w_r2, out);
}

// Round 5
// 604.779 us; speedup vs baseline: 2.9110x; 1.2148x over previous
//
#include <hip/hip_runtime.h>
#include <math.h>

// Problem constants (fixed by setup_inputs in the reference)
#define IN   128
#define HID  256
#define OUT  64
#define N0   400000
#define N1T  40000
#define N2T  4000
#define E1   640000
#define E2   64000

// ---------------------------------------------------------------------------
// hist: count in-degree of every target node for both edge sets.
// ---------------------------------------------------------------------------
__global__ __launch_bounds__(256) void hist_kernel(
    const int* __restrict__ dst1, const int* __restrict__ dst2,
    int* __restrict__ cnt1, int* __restrict__ cnt2)
{
    int e = blockIdx.x * 256 + threadIdx.x;
    if (e < E1) {
        atomicAdd(&cnt1[dst1[e]], 1);
    } else if (e < E1 + E2) {
        atomicAdd(&cnt2[dst2[e - E1]], 1);
    }
}

// ---------------------------------------------------------------------------
// scan2: both exclusive scans in one launch. block 0 -> set 1, block 1 -> set 2.
// ---------------------------------------------------------------------------
__global__ __launch_bounds__(1024) void scan2_kernel(
    const int* __restrict__ cnt1, int* __restrict__ off1, int* __restrict__ cur1,
    const int* __restrict__ cnt2, int* __restrict__ off2, int* __restrict__ cur2)
{
    const int* cnt; int* off; int* cur; int n;
    if (blockIdx.x == 0) { cnt = cnt1; off = off1; cur = cur1; n = N1T; }
    else                 { cnt = cnt2; off = off2; cur = cur2; n = N2T; }

    __shared__ int sums[1024];
    const int t = threadIdx.x;
    const int chunk = (n + 1023) >> 10;
    const int begin = min(t * chunk, n);
    const int end = min(begin + chunk, n);

    int s = 0;
    for (int i = begin; i < end; ++i) s += cnt[i];
    sums[t] = s;
    __syncthreads();

    for (int d = 1; d < 1024; d <<= 1) {
        int tmp = (t >= d) ? sums[t - d] : 0;
        __syncthreads();
        sums[t] += tmp;
        __syncthreads();
    }

    int run = sums[t] - s;  // exclusive prefix at chunk start
    for (int i = begin; i < end; ++i) {
        off[i] = run;
        cur[i] = run;
        run += cnt[i];
    }
    if (end == n && begin < end) off[n] = run;
}

// ---------------------------------------------------------------------------
// scatter_idx: bucket edges by dst (CSR build). Order within bucket is
// nondeterministic (atomic cursor) — only affects fp summation order.
// ---------------------------------------------------------------------------
__global__ __launch_bounds__(256) void scatter_idx_kernel(
    const int* __restrict__ src1, const int* __restrict__ dst1,
    const int* __restrict__ src2, const int* __restrict__ dst2,
    int* __restrict__ cur1, int* __restrict__ cur2,
    int* __restrict__ ss1, int* __restrict__ ss2)
{
    int e = blockIdx.x * 256 + threadIdx.x;
    if (e < E1) {
        int pos = atomicAdd(&cur1[dst1[e]], 1);
        ss1[pos] = src1[e];
    } else if (e < E1 + E2) {
        int ee = e - E1;
        int pos = atomicAdd(&cur2[dst2[ee]], 1);
        ss2[pos] = src2[ee];
    }
}

// ---------------------------------------------------------------------------
// gather1: per target row (one wave), agg1[row] = mean of x[ss[...]] rows.
// Lane-parallel index prefetch + shfl broadcast; 4x unrolled row loads.
// 64 lanes x float2 = 128 cols.
// ---------------------------------------------------------------------------
__global__ __launch_bounds__(256) void gather1_kernel(
    const float* __restrict__ x,
    const int* __restrict__ off, const int* __restrict__ ss,
    float* __restrict__ agg)
{
    int row = blockIdx.x * 4 + (threadIdx.x >> 6);
    if (row >= N1T) return;
    int lane = threadIdx.x & 63;
    int b = off[row], en = off[row + 1];

    float2 acc = make_float2(0.0f, 0.0f);
    for (int base = b; base < en; base += 64) {
        int cnt = min(64, en - base);
        int myidx = (lane < cnt) ? ss[base + lane] : 0;
        int e = 0;
        for (; e + 4 <= cnt; e += 4) {
            int s0 = __shfl(myidx, e);
            int s1 = __shfl(myidx, e + 1);
            int s2 = __shfl(myidx, e + 2);
            int s3 = __shfl(myidx, e + 3);
            float2 v0 = reinterpret_cast<const float2*>(x + (size_t)s0 * IN)[lane];
            float2 v1 = reinterpret_cast<const float2*>(x + (size_t)s1 * IN)[lane];
            float2 v2 = reinterpret_cast<const float2*>(x + (size_t)s2 * IN)[lane];
            float2 v3 = reinterpret_cast<const float2*>(x + (size_t)s3 * IN)[lane];
            acc.x += v0.x + v1.x + v2.x + v3.x;
            acc.y += v0.y + v1.y + v2.y + v3.y;
        }
        for (; e < cnt; ++e) {
            int s = __shfl(myidx, e);
            float2 v = reinterpret_cast<const float2*>(x + (size_t)s * IN)[lane];
            acc.x += v.x;
            acc.y += v.y;
        }
    }
    float inv = 1.0f / fmaxf((float)(en - b), 1.0f);
    acc.x *= inv;
    acc.y *= inv;
    reinterpret_cast<float2*>(agg + (size_t)row * IN)[lane] = acc;
}

// ---------------------------------------------------------------------------
// gather2: per target row (one wave), agg2[row] = mean of h[ss[...]] rows.
// 64 lanes x float4 = 256 cols.
// ---------------------------------------------------------------------------
__global__ __launch_bounds__(256) void gather2_kernel(
    const float* __restrict__ h,
    const int* __restrict__ off, const int* __restrict__ ss,
    float* __restrict__ agg)
{
    int row = blockIdx.x * 4 + (threadIdx.x >> 6);
    if (row >= N2T) return;
    int lane = threadIdx.x & 63;
    int b = off[row], en = off[row + 1];

    float4 acc = make_float4(0.0f, 0.0f, 0.0f, 0.0f);
    for (int base = b; base < en; base += 64) {
        int cnt = min(64, en - base);
        int myidx = (lane < cnt) ? ss[base + lane] : 0;
        int e = 0;
        for (; e + 2 <= cnt; e += 2) {
            int s0 = __shfl(myidx, e);
            int s1 = __shfl(myidx, e + 1);
            float4 v0 = reinterpret_cast<const float4*>(h + (size_t)s0 * HID)[lane];
            float4 v1 = reinterpret_cast<const float4*>(h + (size_t)s1 * HID)[lane];
            acc.x += v0.x + v1.x; acc.y += v0.y + v1.y;
            acc.z += v0.z + v1.z; acc.w += v0.w + v1.w;
        }
        for (; e < cnt; ++e) {
            int s = __shfl(myidx, e);
            float4 v = reinterpret_cast<const float4*>(h + (size_t)s * HID)[lane];
            acc.x += v.x; acc.y += v.y; acc.z += v.z; acc.w += v.w;
        }
    }
    float inv = 1.0f / fmaxf((float)(en - b), 1.0f);
    acc.x *= inv; acc.y *= inv; acc.z *= inv; acc.w *= inv;
    reinterpret_cast<float4*>(agg + (size_t)row * HID)[lane] = acc;
}

// ---------------------------------------------------------------------------
// layer1: register-tiled GEMM. C[40000x256] = [agg1 | x] @ [w_l1; w_r1] + b, relu.
// BM=64, BN=256 (full), K=256. A-tile transposed in LDS: A_s[k][m].
// 256 threads: wave = mgrp (16 rows), lane = ngrp (4 cols). 16x4 acc/thread.
// Per k: 4 uniform ds_read_b128 (broadcast) + 1 coalesced float4 W load + 64 FMA.
// ---------------------------------------------------------------------------
__global__ __launch_bounds__(256) void layer1_kernel(
    const float* __restrict__ x,
    const float* __restrict__ agg,
    const float* __restrict__ w_l, const float* __restrict__ b_l,
    const float* __restrict__ w_r, float* __restrict__ h)
{
    __shared__ float A_s[256][64];   // [k][m]; k<128: agg row-k, k>=128: x row-(k-128)
    const int r0 = blockIdx.x * 64;
    const int tid = threadIdx.x;

    // stage A (transposed). Write bank conflicts are amortized (<2% of k-loop).
    for (int i = tid; i < 64 * 32; i += 256) {
        int r = i >> 5;      // 0..63
        int c4 = i & 31;     // 0..31 float4 within a 128-float row
        float4 va = reinterpret_cast<const float4*>(agg + (size_t)(r0 + r) * IN)[c4];
        float4 vx = reinterpret_cast<const float4*>(x + (size_t)(r0 + r) * IN)[c4];
        int k = c4 * 4;
        A_s[k + 0][r] = va.x; A_s[k + 1][r] = va.y;
        A_s[k + 2][r] = va.z; A_s[k + 3][r] = va.w;
        A_s[128 + k + 0][r] = vx.x; A_s[128 + k + 1][r] = vx.y;
        A_s[128 + k + 2][r] = vx.z; A_s[128 + k + 3][r] = vx.w;
    }
    __syncthreads();

    const int ngrp = tid & 63;   // cols ngrp*4 .. ngrp*4+3
    const int mgrp = tid >> 6;   // rows mgrp*16 .. mgrp*16+15

    float acc[16][4];
#pragma unroll
    for (int m = 0; m < 16; ++m)
#pragma unroll
        for (int j = 0; j < 4; ++j) acc[m][j] = 0.0f;

    const float4* wl4 = reinterpret_cast<const float4*>(w_l);
    const float4* wr4 = reinterpret_cast<const float4*>(w_r);

#pragma unroll 4
    for (int k = 0; k < 128; ++k) {
        float4 w = wl4[k * 64 + ngrp];
        const float4* ap = reinterpret_cast<const float4*>(&A_s[k][mgrp * 16]);
        float4 a0 = ap[0], a1 = ap[1], a2 = ap[2], a3 = ap[3];
        float am[16] = {a0.x, a0.y, a0.z, a0.w, a1.x, a1.y, a1.z, a1.w,
                        a2.x, a2.y, a2.z, a2.w, a3.x, a3.y, a3.z, a3.w};
#pragma unroll
        for (int m = 0; m < 16; ++m) {
            acc[m][0] += am[m] * w.x;
            acc[m][1] += am[m] * w.y;
            acc[m][2] += am[m] * w.z;
            acc[m][3] += am[m] * w.w;
        }
    }
#pragma unroll 4
    for (int k = 0; k < 128; ++k) {
        float4 w = wr4[k * 64 + ngrp];
        const float4* ap = reinterpret_cast<const float4*>(&A_s[128 + k][mgrp * 16]);
        float4 a0 = ap[0], a1 = ap[1], a2 = ap[2], a3 = ap[3];
        float am[16] = {a0.x, a0.y, a0.z, a0.w, a1.x, a1.y, a1.z, a1.w,
                        a2.x, a2.y, a2.z, a2.w, a3.x, a3.y, a3.z, a3.w};
#pragma unroll
        for (int m = 0; m < 16; ++m) {
            acc[m][0] += am[m] * w.x;
            acc[m][1] += am[m] * w.y;
            acc[m][2] += am[m] * w.z;
            acc[m][3] += am[m] * w.w;
        }
    }

    float4 b = reinterpret_cast<const float4*>(b_l)[ngrp];
#pragma unroll
    for (int m = 0; m < 16; ++m) {
        float4 o;
        o.x = fmaxf(acc[m][0] + b.x, 0.0f);
        o.y = fmaxf(acc[m][1] + b.y, 0.0f);
        o.z = fmaxf(acc[m][2] + b.z, 0.0f);
        o.w = fmaxf(acc[m][3] + b.w, 0.0f);
        reinterpret_cast<float4*>(h + (size_t)(r0 + mgrp * 16 + m) * HID)[ngrp] = o;
    }
}

// ---------------------------------------------------------------------------
// layer2 + log_softmax: one wave (64 threads) per output row. agg2 already mean.
// ---------------------------------------------------------------------------
__global__ __launch_bounds__(64) void layer2_kernel(
    const float* __restrict__ h,
    const float* __restrict__ agg,
    const float* __restrict__ w_l, const float* __restrict__ b_l,
    const float* __restrict__ w_r, float* __restrict__ out)
{
    __shared__ float a_s[HID];
    __shared__ float h_s[HID];
    const int i = blockIdx.x;
    const int j = threadIdx.x;  // 0..63

    const float4* ar = reinterpret_cast<const float4*>(agg + (size_t)i * HID);
    const float4* hr = reinterpret_cast<const float4*>(h + (size_t)i * HID);
    reinterpret_cast<float4*>(a_s)[j] = ar[j];
    reinterpret_cast<float4*>(h_s)[j] = hr[j];
    __syncthreads();

    float acc = b_l[j];
    for (int k = 0; k < HID; ++k) {
        acc += a_s[k] * w_l[k * OUT + j] + h_s[k] * w_r[k * OUT + j];
    }

    // wave-wide (64-lane) log_softmax
    float m = acc;
#pragma unroll
    for (int off = 32; off; off >>= 1) m = fmaxf(m, __shfl_xor(m, off));
    float ex = expf(acc - m);
#pragma unroll
    for (int off = 32; off; off >>= 1) ex += __shfl_xor(ex, off);
    out[(size_t)i * OUT + j] = acc - m - logf(ex);
}

// ---------------------------------------------------------------------------
extern "C" void kernel_launch(void* const* d_in, const int* in_sizes, int n_in,
                              void* d_out, int out_size, void* d_ws, size_t ws_size,
                              hipStream_t stream)
{
    const float* x    = (const float*)d_in[0];
    const int*   src1 = (const int*)  d_in[1];
    const int*   dst1 = (const int*)  d_in[2];
    const int*   src2 = (const int*)  d_in[3];
    const int*   dst2 = (const int*)  d_in[4];
    const float* w_l1 = (const float*)d_in[5];
    const float* b_l1 = (const float*)d_in[6];
    const float* w_r1 = (const float*)d_in[7];
    const float* w_l2 = (const float*)d_in[8];
    const float* b_l2 = (const float*)d_in[9];
    const float* w_r2 = (const float*)d_in[10];
    float* out = (float*)d_out;

    // Workspace layout:
    // ints:  [cnt1:N1T | cnt2:N2T | off1:N1T+1 | off2:N2T+1 | cur1:N1T | cur2:N2T | ss1:E1 | ss2:E2]
    // floats:[agg1:N1T*IN | agg2:N2T*HID | h:N1T*HID]
    int* ws_i = (int*)d_ws;
    int* cnt1 = ws_i;
    int* cnt2 = cnt1 + N1T;
    int* off1 = cnt2 + N2T;
    int* off2 = off1 + N1T + 1;
    int* cur1 = off2 + N2T + 1;
    int* cur2 = cur1 + N1T;
    int* ss1  = cur2 + N2T;
    int* ss2  = ss1 + E1;
    float* agg1 = (float*)(ss2 + E2);
    float* agg2 = agg1 + (size_t)N1T * IN;
    float* h    = agg2 + (size_t)N2T * HID;

    // zero only the histogram counters
    hipMemsetAsync(cnt1, 0, (N1T + N2T) * sizeof(int), stream);

    const int ET = E1 + E2;
    hist_kernel<<<(ET + 255) / 256, 256, 0, stream>>>(dst1, dst2, cnt1, cnt2);
    scan2_kernel<<<2, 1024, 0, stream>>>(cnt1, off1, cur1, cnt2, off2, cur2);
    scatter_idx_kernel<<<(ET + 255) / 256, 256, 0, stream>>>(src1, dst1, src2, dst2,
                                                             cur1, cur2, ss1, ss2);
    gather1_kernel<<<(N1T + 3) / 4, 256, 0, stream>>>(x, off1, ss1, agg1);
    layer1_kernel<<<N1T / 64, 256, 0, stream>>>(x, agg1, w_l1, b_l1, w_r1, h);
    gather2_kernel<<<(N2T + 3) / 4, 256, 0, stream>>>(h, off2, ss2, agg2);
    layer2_kernel<<<N2T, 64, 0, stream>>>(h, agg2, w_l2, b_l2, w_r2, out);
}